// Round 17
// baseline (210.552 us; speedup 1.0000x reference)
//
#include <hip/hip_runtime.h>
#include <math.h>

// Microfacet (GGX + Fresnel) elementwise BRDF eval.
// R5 (48B stride, IEEE div)      ~50us
// R8 (96B stride, rcp/rsq)       ~52us   -> not VALU-bound
// R10 (unit-stride LDS staged)   ~51us   -> not coalescing-bound
// R11 (nontemporal ld+st)        ~50us   -> not allocation-policy-bound
// All ~3.0 TB/s effective; harness write-only fill does 6.9 TB/s in the same
// graph. Hypothesis: window throttled by external memory-system state (LLC
// dirty-line drain / cross-XCD dirty-L2 probes from the harness's d_in
// restore + 402MB poison fills, invisible to TCC counters).
// R12 = DIAGNOSTIC: main kernel byte-identical to R11 + an appended 100MB
// unit-stride d_in->d_ws streaming copy. Marginal dur_us of the copy measures
// the in-situ streaming rate: ~33us => theory wrong (kernel-side problem
// remains); ~65us => in-situ rate ~3 TB/s confirmed => R11 is at the in-situ
// roofline.

typedef float v4f __attribute__((ext_vector_type(4)));

__device__ __forceinline__ float brdf_scale(
    float lx, float ly, float lz,
    float vx, float vy, float vz,
    float a2, float eta2)
{
    float hx = lx + vx, hy = ly + vy, hz = lz + vz;
    float rn = __builtin_amdgcn_rsqf(hx * hx + hy * hy + hz * hz);
    hx *= rn; hy *= rn; hz *= rn;

    float cos_nh = hz;
    float c = hx * vx + hy * vy + hz * vz;   // cos_hv

    float dd = cos_nh * cos_nh * (a2 - 1.0f) + 1.0f;
    float D = a2 * __builtin_amdgcn_rcpf(3.14159274f * dd * dd);

    float g2 = eta2 + c * c - 1.0f;
    float g = sqrtf(fmaxf(g2, 1e-12f));
    float a = (g - c) * __builtin_amdgcn_rcpf(g + c);
    float b = (c * (g + c) - 1.0f) * __builtin_amdgcn_rcpf(c * (g - c) + 1.0f);
    float F = (g2 > 0.0f) ? (0.5f * a * a * (1.0f + b * b)) : 1.0f;

    // G = cos_nl*cos_nv cancels exactly with the 4*cos_nl*cos_nv denominator.
    return D * F * 0.25f;
}

__global__ __launch_bounds__(256) void microfacet_kernel(
    const v4f* __restrict__ in4,           // [N*6/4]
    const float* __restrict__ base_color,  // [3]
    const float* __restrict__ alpha,       // [1]
    const float* __restrict__ eta,         // [1]
    v4f* __restrict__ out4,                // [N*3/4]
    int n_in4, int n_out4)
{
    __shared__ v4f lds[768];               // 512 points/block, 12 KB

    const int tid = threadIdx.x;
    const int in_base  = blockIdx.x * 768;
    const int out_base = blockIdx.x * 384;

    const float al = alpha[0];
    const float a2 = al * al;
    const float et = eta[0];
    const float eta2 = et * et;
    const float lin0 = powf(base_color[0], 2.2f);
    const float lin1 = powf(base_color[1], 2.2f);
    const float lin2 = powf(base_color[2], 2.2f);

    // 1) global -> LDS, unit-stride, nontemporal
#pragma unroll
    for (int k = 0; k < 3; ++k) {
        const int g = in_base + k * 256 + tid;
        v4f q = (v4f){0.f, 0.f, 0.f, 1.f};
        if (g < n_in4) q = __builtin_nontemporal_load(&in4[g]);
        lds[k * 256 + tid] = q;
    }
    __syncthreads();

    // 2) LDS -> regs: thread t owns points 2t,2t+1
    const v4f q0 = lds[3 * tid + 0];
    const v4f q1 = lds[3 * tid + 1];
    const v4f q2 = lds[3 * tid + 2];

    // 3) compute
    const float sA = brdf_scale(q0.x, q0.y, q0.z, q0.w, q1.x, q1.y, a2, eta2);
    const float sB = brdf_scale(q1.z, q1.w, q2.x, q2.y, q2.z, q2.w, a2, eta2);

    __syncthreads();

    // 4) regs -> LDS out region
    float* lf = (float*)lds;
    lf[6 * tid + 0] = lin0 * sA;
    lf[6 * tid + 1] = lin1 * sA;
    lf[6 * tid + 2] = lin2 * sA;
    lf[6 * tid + 3] = lin0 * sB;
    lf[6 * tid + 4] = lin1 * sB;
    lf[6 * tid + 5] = lin2 * sB;
    __syncthreads();

    // 5) LDS -> global, unit-stride, nontemporal
    {
        const int g = out_base + tid;
        if (g < n_out4) __builtin_nontemporal_store(lds[tid], &out4[g]);
        if (tid < 128) {
            const int g2 = out_base + 256 + tid;
            if (g2 < n_out4) __builtin_nontemporal_store(lds[256 + tid], &out4[g2]);
        }
    }
}

// DIAGNOSTIC: plain unit-stride streaming copy d_in -> d_ws (scratch).
// Marginal cost of this dispatch = in-situ streaming rate probe.
__global__ __launch_bounds__(256) void streamcopy_kernel(
    const v4f* __restrict__ src, v4f* __restrict__ dst, int n4)
{
    int i = blockIdx.x * blockDim.x + threadIdx.x;
    const int stride = gridDim.x * blockDim.x;
    for (; i < n4; i += stride) dst[i] = src[i];
}

extern "C" void kernel_launch(void* const* d_in, const int* in_sizes, int n_in,
                              void* d_out, int out_size, void* d_ws, size_t ws_size,
                              hipStream_t stream) {
    const v4f* in4 = (const v4f*)d_in[0];
    const float* base_color = (const float*)d_in[1];
    const float* alpha = (const float*)d_in[2];
    const float* eta = (const float*)d_in[3];
    v4f* out4 = (v4f*)d_out;

    const int n = in_sizes[0] / 6;        // points (4194304)
    const int n_in4 = in_sizes[0] / 4;    // 6291456 float4 = 100.7 MB
    const int n_out4 = out_size / 4;

    const int block = 256;
    const int grid = (n + 511) / 512;     // 8192 blocks
    microfacet_kernel<<<grid, block, 0, stream>>>(in4, base_color, alpha, eta,
                                                  out4, n_in4, n_out4);

    // Diagnostic copy: 100MB read (d_in) + 100MB write (d_ws scratch).
    const int n_copy4 = (int)((ws_size / 16 < (size_t)n_in4) ? ws_size / 16
                                                             : (size_t)n_in4);
    if (n_copy4 > 0) {
        streamcopy_kernel<<<2048, 256, 0, stream>>>(in4, (v4f*)d_ws, n_copy4);
    }
}

// Round 18
// 164.510 us; speedup vs baseline: 1.2799x; 1.2799x over previous
//
#include <hip/hip_runtime.h>
#include <math.h>

// Microfacet (GGX + Fresnel) elementwise BRDF eval. — FINAL (R11 form)
//
// Evidence chain:
//  R5 (48B stride, IEEE div)     ~50us
//  R8 (96B stride, rcp/rsq)      ~52us  -> not VALU-bound
//  R10 (unit-stride LDS staged)  ~51us  -> not coalescing-bound
//  R11 (nontemporal ld+st)       ~50us  -> not allocation-policy-bound
//  R17 DIAGNOSTIC: plain unit-stride 100MB copy in the same graph slot runs
//    59us @ 3.4 TB/s total (read stream 1.7 TB/s) vs 6.29 TB/s standalone.
//    => in-situ read-stream ceiling ~1.7-2.0 TB/s (harness restore+poison
//    leaves input lines dirty; reads pay probe/writeback). Our kernel reads
//    100MB at 2.0 TB/s — ABOVE the known-good comparator. 50us IS the
//    in-situ roofline; write path (6.9 TB/s fill) is not the limiter.

typedef float v4f __attribute__((ext_vector_type(4)));

__device__ __forceinline__ float brdf_scale(
    float lx, float ly, float lz,
    float vx, float vy, float vz,
    float a2, float eta2)
{
    float hx = lx + vx, hy = ly + vy, hz = lz + vz;
    float rn = __builtin_amdgcn_rsqf(hx * hx + hy * hy + hz * hz);
    hx *= rn; hy *= rn; hz *= rn;

    float cos_nh = hz;
    float c = hx * vx + hy * vy + hz * vz;   // cos_hv

    float dd = cos_nh * cos_nh * (a2 - 1.0f) + 1.0f;
    float D = a2 * __builtin_amdgcn_rcpf(3.14159274f * dd * dd);

    float g2 = eta2 + c * c - 1.0f;
    float g = sqrtf(fmaxf(g2, 1e-12f));
    float a = (g - c) * __builtin_amdgcn_rcpf(g + c);
    float b = (c * (g + c) - 1.0f) * __builtin_amdgcn_rcpf(c * (g - c) + 1.0f);
    float F = (g2 > 0.0f) ? (0.5f * a * a * (1.0f + b * b)) : 1.0f;

    // G = cos_nl*cos_nv cancels exactly with the 4*cos_nl*cos_nv denominator.
    return D * F * 0.25f;
}

__global__ __launch_bounds__(256) void microfacet_kernel(
    const v4f* __restrict__ in4,           // [N*6/4]
    const float* __restrict__ base_color,  // [3]
    const float* __restrict__ alpha,       // [1]
    const float* __restrict__ eta,         // [1]
    v4f* __restrict__ out4,                // [N*3/4]
    int n_in4, int n_out4)
{
    __shared__ v4f lds[768];               // 512 points/block, 12 KB

    const int tid = threadIdx.x;
    const int in_base  = blockIdx.x * 768;
    const int out_base = blockIdx.x * 384;

    const float al = alpha[0];
    const float a2 = al * al;
    const float et = eta[0];
    const float eta2 = et * et;
    const float lin0 = powf(base_color[0], 2.2f);
    const float lin1 = powf(base_color[1], 2.2f);
    const float lin2 = powf(base_color[2], 2.2f);

    // 1) global -> LDS, unit-stride, nontemporal
#pragma unroll
    for (int k = 0; k < 3; ++k) {
        const int g = in_base + k * 256 + tid;
        v4f q = (v4f){0.f, 0.f, 0.f, 1.f};
        if (g < n_in4) q = __builtin_nontemporal_load(&in4[g]);
        lds[k * 256 + tid] = q;
    }
    __syncthreads();

    // 2) LDS -> regs: thread t owns points 2t,2t+1
    const v4f q0 = lds[3 * tid + 0];
    const v4f q1 = lds[3 * tid + 1];
    const v4f q2 = lds[3 * tid + 2];

    // 3) compute
    const float sA = brdf_scale(q0.x, q0.y, q0.z, q0.w, q1.x, q1.y, a2, eta2);
    const float sB = brdf_scale(q1.z, q1.w, q2.x, q2.y, q2.z, q2.w, a2, eta2);

    __syncthreads();

    // 4) regs -> LDS out region
    float* lf = (float*)lds;
    lf[6 * tid + 0] = lin0 * sA;
    lf[6 * tid + 1] = lin1 * sA;
    lf[6 * tid + 2] = lin2 * sA;
    lf[6 * tid + 3] = lin0 * sB;
    lf[6 * tid + 4] = lin1 * sB;
    lf[6 * tid + 5] = lin2 * sB;
    __syncthreads();

    // 5) LDS -> global, unit-stride, nontemporal
    {
        const int g = out_base + tid;
        if (g < n_out4) __builtin_nontemporal_store(lds[tid], &out4[g]);
        if (tid < 128) {
            const int g2 = out_base + 256 + tid;
            if (g2 < n_out4) __builtin_nontemporal_store(lds[256 + tid], &out4[g2]);
        }
    }
}

extern "C" void kernel_launch(void* const* d_in, const int* in_sizes, int n_in,
                              void* d_out, int out_size, void* d_ws, size_t ws_size,
                              hipStream_t stream) {
    const v4f* in4 = (const v4f*)d_in[0];
    const float* base_color = (const float*)d_in[1];
    const float* alpha = (const float*)d_in[2];
    const float* eta = (const float*)d_in[3];
    v4f* out4 = (v4f*)d_out;

    const int n = in_sizes[0] / 6;        // points (4194304)
    const int n_in4 = in_sizes[0] / 4;
    const int n_out4 = out_size / 4;

    const int block = 256;
    const int grid = (n + 511) / 512;     // 8192 blocks
    microfacet_kernel<<<grid, block, 0, stream>>>(in4, base_color, alpha, eta,
                                                  out4, n_in4, n_out4);
}